// Round 6
// baseline (79.295 us; speedup 1.0000x reference)
//
#include <hip/hip_runtime.h>
#include <stdint.h>

#define S_LEN 2048
#define NTILE 32

typedef float f32x4 __attribute__((ext_vector_type(4)));
typedef float f32x16 __attribute__((ext_vector_type(16)));
typedef short bf16x8 __attribute__((ext_vector_type(8)));

__device__ __forceinline__ uint16_t f2bf(float f) {
    uint32_t u = __float_as_uint(f);
    return (uint16_t)((u + 0x7FFFu + ((u >> 16) & 1u)) >> 16);
}

#define AS3PTR(p) ((__attribute__((address_space(3))) uint32_t*)(uintptr_t)(p))
#define AS1PTR(p) ((const __attribute__((address_space(1))) uint32_t*)(uintptr_t)(p))

// ---------------- fused prepass ----------------
// K image (8KB per bh,kt): 16B block (dc,h,key) at ((dc*2+h)*64+key)*16 =
//   bf16 K[bh][64kt+key][16dc+8h+0..7]           (A-frag of QK, contiguous read)
// V image (8KB per bh,kt): 16B block (ku,h,d) at ((ku*2+h)*64+d)*16 =
//   bf16 V[bh][64kt+16ku+8h+0..7][d]             (B-frag of PV, contiguous read)
// Mp u16 per (b,qt,kt,w,lane): bit r = mask[b][qt*64+32qw+(l&31)]
//   [kt*64+32kw+(r&3)+8(r>>2)+4(l>>5)] > 0.5,  w = qw*2+kw
__global__ __launch_bounds__(256)
void prep_all(const float* __restrict__ K, const float* __restrict__ V,
              const float* __restrict__ M, uint8_t* __restrict__ Kd,
              uint8_t* __restrict__ Vd, uint16_t* __restrict__ Mp)
{
    __shared__ float mt[4096];
    const int bid = blockIdx.x;
    const int tid = threadIdx.x;
    if (bid < 2048) {                       // ---- K ----
        int flat = bid * 256 + tid;
        int s = flat & 511, tile = flat >> 9;
        int key = s >> 3, dc = (s >> 1) & 3, h = s & 1;
        int kt = tile & 31, bh = tile >> 5;
        const float* src = K + (((size_t)bh * S_LEN + kt * 64 + key) << 6) + dc * 16 + h * 8;
        f32x4 a = *(const f32x4*)src;
        f32x4 b = *(const f32x4*)(src + 4);
        bf16x8 o;
        o[0] = (short)f2bf(a[0]); o[1] = (short)f2bf(a[1]);
        o[2] = (short)f2bf(a[2]); o[3] = (short)f2bf(a[3]);
        o[4] = (short)f2bf(b[0]); o[5] = (short)f2bf(b[1]);
        o[6] = (short)f2bf(b[2]); o[7] = (short)f2bf(b[3]);
        *(bf16x8*)(Kd + ((size_t)tile << 13) + (((dc * 2 + h) * 64 + key) << 4)) = o;
    } else if (bid < 4096) {                // ---- V ----
        int flat = (bid - 2048) * 256 + tid;
        int s = flat & 511, tile = flat >> 9;
        int d = s & 63, h = (s >> 6) & 1, ku = s >> 7;
        int kt = tile & 31, bh = tile >> 5;
        const float* src = V + (((size_t)bh * S_LEN + kt * 64 + ku * 16 + h * 8) << 6) + d;
        bf16x8 o;
        #pragma unroll
        for (int j = 0; j < 8; ++j) o[j] = (short)f2bf(src[j << 6]);
        *(bf16x8*)(Vd + ((size_t)tile << 13) + (((ku * 2 + h) * 64 + d) << 4)) = o;
    } else {                                // ---- mask ----
        int mid = bid - 4096;               // (b, qt, kt)
        int b = mid >> 10, qt = (mid >> 5) & 31, kt = mid & 31;
        int row = tid >> 2, cc = tid & 3;
        const float* src = M + ((size_t)(b * S_LEN + qt * 64 + row) * S_LEN) + kt * 64;
        #pragma unroll
        for (int i = 0; i < 4; ++i)
            *(f32x4*)&mt[(row << 6) + cc * 16 + i * 4] =
                *(const f32x4*)(src + cc * 16 + i * 4);
        __syncthreads();
        int l = tid & 63, w = tid >> 6;
        int qw = w >> 1, kw = w & 1, h = l >> 5, l31 = l & 31;
        uint32_t m = 0;
        #pragma unroll
        for (int r = 0; r < 16; ++r) {
            int keyl = 32 * kw + (r & 3) + 8 * (r >> 2) + 4 * h;
            m |= (mt[((32 * qw + l31) << 6) + keyl] > 0.5f) << r;
        }
        Mp[((size_t)mid << 8) + tid] = (uint16_t)m;
    }
}

// ---------------- fused masked attention (2x2 wave split, 32x32x16 MFMA) ----------------
#define K_OFF 0        // 2 x 8192 double-buffered K image
#define V_OFF 16384    // 2 x 8192 double-buffered V image

__global__ __launch_bounds__(256, 4)
void attn_fwd(const float* __restrict__ Q, const uint8_t* __restrict__ Kd,
              const uint8_t* __restrict__ Vd, const uint16_t* __restrict__ Mp,
              float* __restrict__ O)
{
    __shared__ __align__(16) uint8_t lds[32768];

    const int tid  = threadIdx.x;
    const int lane = tid & 63;
    const int w    = tid >> 6;
    const int qw   = w >> 1;    // q-half   [32qw, 32qw+32)
    const int kw   = w & 1;     // key-half [32kw, 32kw+32) of each 64-key tile
    const int h    = lane >> 5;
    const int l31  = lane & 31;

    const int bid0 = blockIdx.x;
    const int bid  = ((bid0 & 7) << 7) + (bid0 >> 3);  // XCD swizzle (1024%8==0)
    const int bh  = bid >> 5;
    const int qt  = bid & 31;
    const int b   = bh >> 3;
    const int q0  = qt << 6;

    // ---- Q B-fragments: qf[dc]: Q[q0+32qw+l31][16dc+8h+j] * QSCL ----
    const float QSCL = 0.125f * 1.44269504088896340736f;  // 1/sqrt(D)*log2(e)
    bf16x8 qf[4];
    {
        const float* qrow = Q + (((size_t)bh * S_LEN + q0 + 32 * qw + l31) << 6);
        #pragma unroll
        for (int dc = 0; dc < 4; ++dc) {
            f32x4 a  = *(const f32x4*)(qrow + dc * 16 + h * 8);
            f32x4 b4 = *(const f32x4*)(qrow + dc * 16 + h * 8 + 4);
            bf16x8 f;
            f[0] = (short)f2bf(a[0] * QSCL);  f[1] = (short)f2bf(a[1] * QSCL);
            f[2] = (short)f2bf(a[2] * QSCL);  f[3] = (short)f2bf(a[3] * QSCL);
            f[4] = (short)f2bf(b4[0] * QSCL); f[5] = (short)f2bf(b4[1] * QSCL);
            f[6] = (short)f2bf(b4[2] * QSCL); f[7] = (short)f2bf(b4[3] * QSCL);
            qf[dc] = f;
        }
    }

    f32x16 acc[2];   // [dblk]: O[q=32qw+(r&3)+8(r>>2)+4h][d=32dblk+l31] partial (this kw)
    acc[0] = (f32x16)(0.f);
    acc[1] = (f32x16)(0.f);
    float lsum = 0.f;  // denominator partial for q = q0+32qw+l31

    const uint8_t*  ktb = Kd + (((size_t)bh * 32) << 13);
    const uint8_t*  vtb = Vd + (((size_t)bh * 32) << 13);
    const uint16_t* mbase = Mp + (((size_t)(b * 32 + qt) * 32) << 8) + (w << 6) + lane;

    auto stage = [&](int buf, int t) {
        #pragma unroll
        for (int i = 0; i < 2; ++i) {
            int off = (i << 12) + (w << 10);           // wave-uniform 1KB chunk
            __builtin_amdgcn_global_load_lds(
                AS1PTR(ktb + ((size_t)t << 13) + off + lane * 16),
                AS3PTR(&lds[K_OFF + (buf << 13) + off]), 16, 0, 0);
            __builtin_amdgcn_global_load_lds(
                AS1PTR(vtb + ((size_t)t << 13) + off + lane * 16),
                AS3PTR(&lds[V_OFF + (buf << 13) + off]), 16, 0, 0);
        }
    };

    stage(0, 0);
    __syncthreads();

    #pragma unroll 2
    for (int kt = 0; kt < NTILE; ++kt) {
        const int buf = kt & 1;
        if (kt + 1 < NTILE) stage(buf ^ 1, kt + 1);   // in flight over compute

        uint32_t mw = mbase[kt << 8];

        // ---- S^T = K Q^T : D-frag lane l, reg r: q=l31, key=32kw+(r&3)+8(r>>2)+4h ----
        const uint8_t* kb = &lds[K_OFF + (buf << 13)];
        f32x16 s = (f32x16)(0.f);
        #pragma unroll
        for (int dc = 0; dc < 4; ++dc) {
            bf16x8 kf = *(const bf16x8*)(kb + (((dc * 2 + h) * 64 + 32 * kw + l31) << 4));
            s = __builtin_amdgcn_mfma_f32_32x32x16_bf16(kf, qf[dc], s, 0, 0, 0);
        }

        // ---- masked exp2 + pack (Q pre-scaled into exp2 domain) ----
        uint32_t pd[8];
        #pragma unroll
        for (int rq = 0; rq < 8; ++rq) {
            float x0 = (mw & (1u << (2 * rq)))     ? s[2 * rq]     : -1000.f;
            float x1 = (mw & (1u << (2 * rq + 1))) ? s[2 * rq + 1] : -1000.f;
            float e0, e1;
            asm("v_exp_f32 %0, %1" : "=v"(e0) : "v"(x0));   // exp2(-1000) -> exact 0
            asm("v_exp_f32 %0, %1" : "=v"(e1) : "v"(x1));
            lsum += e0 + e1;
            asm("v_cvt_pk_bf16_f32 %0, %1, %2" : "=v"(pd[rq]) : "v"(e0), "v"(e1));
        }

        // ---- P D-frag -> A-frag via permlane32_swap (dst.hi <-> src.lo) ----
        // chunk u (16 keys): dword m = keys 32kw+16u+8h+2m,2m+1 after swapping
        #pragma unroll
        for (int u = 0; u < 2; ++u) {
            asm("v_permlane32_swap_b32 %0, %1" : "+v"(pd[4 * u]),     "+v"(pd[4 * u + 2]));
            asm("v_permlane32_swap_b32 %0, %1" : "+v"(pd[4 * u + 1]), "+v"(pd[4 * u + 3]));
        }

        // ---- O += P V : A = P chunk, B = V image frag ----
        const uint8_t* vbuf = &lds[V_OFF + (buf << 13)];
        #pragma unroll
        for (int u = 0; u < 2; ++u) {
            union { uint32_t d[4]; bf16x8 v; } pa;
            pa.d[0] = pd[4 * u]; pa.d[1] = pd[4 * u + 1];
            pa.d[2] = pd[4 * u + 2]; pa.d[3] = pd[4 * u + 3];
            #pragma unroll
            for (int dblk = 0; dblk < 2; ++dblk) {
                bf16x8 vf = *(const bf16x8*)(vbuf +
                    ((((kw * 2 + u) * 2 + h) * 64 + 32 * dblk + l31) << 4));
                acc[dblk] = __builtin_amdgcn_mfma_f32_32x32x16_bf16(pa.v, vf, acc[dblk], 0, 0, 0);
            }
        }

        __syncthreads();   // next tile staged (vmcnt drained); buf reads complete
    }

    // ---- epilogue: reduce over h-halves and kw pair, normalize, store ----
    lsum += __shfl_xor(lsum, 32, 64);

    float* ex  = (float*)lds;             // 2 x 8KB acc exchange (per qw)
    float* ex2 = (float*)(lds + 16384);   // 64 floats lsum exchange
    if (kw == 1) {
        #pragma unroll
        for (int dblk = 0; dblk < 2; ++dblk)
            #pragma unroll
            for (int rq = 0; rq < 4; ++rq) {
                f32x4 v = { acc[dblk][4 * rq], acc[dblk][4 * rq + 1],
                            acc[dblk][4 * rq + 2], acc[dblk][4 * rq + 3] };
                *(f32x4*)&ex[(qw << 11) + (((dblk << 2) + rq) << 8) + (lane << 2)] = v;
            }
        if (lane < 32) ex2[(qw << 5) + lane] = lsum;
    }
    __syncthreads();
    if (kw == 0) {
        #pragma unroll
        for (int dblk = 0; dblk < 2; ++dblk)
            #pragma unroll
            for (int rq = 0; rq < 4; ++rq) {
                f32x4 v = *(const f32x4*)&ex[(qw << 11) + (((dblk << 2) + rq) << 8) + (lane << 2)];
                acc[dblk][4 * rq]     += v[0];
                acc[dblk][4 * rq + 1] += v[1];
                acc[dblk][4 * rq + 2] += v[2];
                acc[dblk][4 * rq + 3] += v[3];
            }
        float l = lsum + ex2[(qw << 5) + l31];
        float linv = (l > 0.f) ? 1.f / l : 0.f;   // all-masked row -> exact 0

        float* obase = O + (((size_t)bh * S_LEN + q0 + 32 * qw) << 6);
        #pragma unroll
        for (int r = 0; r < 16; ++r) {
            int qloc = (r & 3) + 8 * (r >> 2) + 4 * h;
            float inv = __shfl(linv, qloc, 64);   // lane qloc holds q=qloc's denom
            obase[(qloc << 6) + l31]      = acc[0][r] * inv;
            obase[(qloc << 6) + 32 + l31] = acc[1][r] * inv;
        }
    }
}

extern "C" void kernel_launch(void* const* d_in, const int* in_sizes, int n_in,
                              void* d_out, int out_size, void* d_ws, size_t ws_size,
                              hipStream_t stream) {
    const float* qs   = (const float*)d_in[0];
    const float* ks   = (const float*)d_in[1];
    const float* vs   = (const float*)d_in[2];
    const float* mask = (const float*)d_in[3];
    float* out = (float*)d_out;
    (void)in_sizes; (void)n_in; (void)out_size; (void)ws_size;

    uint8_t* ws = (uint8_t*)d_ws;
    uint8_t* Kd = ws;                                   // 8 MiB
    uint8_t* Vd = ws + (8u << 20);                      // 8 MiB
    uint16_t* Mp = (uint16_t*)(ws + (16u << 20));       // 2 MiB

    // 2048 K-blocks + 2048 V-blocks + 4096 mask-blocks
    hipLaunchKernelGGL(prep_all, dim3(8192), dim3(256), 0, stream,
                       ks, vs, mask, Kd, Vd, Mp);
    hipLaunchKernelGGL(attn_fwd, dim3(1024), dim3(256), 0, stream,
                       qs, Kd, Vd, Mp, out);
}